// Round 2
// baseline (748.155 us; speedup 1.0000x reference)
//
#include <hip/hip_runtime.h>
#include <hip/hip_bf16.h>

#define Bn 8
#define Nn 256
#define Fn 128
#define Dn 128

typedef __bf16 bf16_t;
typedef bf16_t bf16x8 __attribute__((ext_vector_type(8)));
typedef float f32x4 __attribute__((ext_vector_type(4)));

// ---------------------------------------------------------------------------
// Generic [rows x 256] x [256 x 128] GEMM, A = [X1 | X2] concat on k.
// fp32 in/out; bf16 MFMA 16x16x32 with fp32 accumulate (threshold is ~2% rel).
// W^T staged in LDS as bf16, XOR-swizzled 16B chunks (conflict-free).
// Each block: 4 waves x 256 rows. Row tile of block b = [b*256, b*256+256).
// ---------------------------------------------------------------------------
__global__ __launch_bounds__(256, 2) void mfma_gemm_kernel(
    const float* __restrict__ X1, const float* __restrict__ X2,
    const float* __restrict__ W, const float* __restrict__ bias,
    float* __restrict__ out)
{
    // element W[k][n] lives at lds[n*256 + ((k>>3) ^ (n&7))*8 + (k&7)]
    __shared__ __align__(16) bf16_t lds[128 * 256];  // 64KB

    const int t = threadIdx.x;

    for (int i = 0; i < 16; ++i) {
        int h  = t + i * 256;          // 4096 chunks of 8
        int k  = h >> 4;               // 0..255
        int n0 = (h & 15) * 8;         // 0..120
        f32x4 v0 = *(const f32x4*)(W + k * 128 + n0);
        f32x4 v1 = *(const f32x4*)(W + k * 128 + n0 + 4);
        int cc = k >> 3, kj = k & 7;
        float vv[8] = {v0[0], v0[1], v0[2], v0[3], v1[0], v1[1], v1[2], v1[3]};
        #pragma unroll
        for (int j = 0; j < 8; ++j) {
            int n  = n0 + j;
            int cp = cc ^ (n & 7);
            lds[n * 256 + cp * 8 + kj] = (bf16_t)vv[j];
        }
    }
    __syncthreads();

    const int wv = t >> 6;
    const int l  = t & 63;
    const int lane16 = l & 15;
    const int quad   = l >> 4;

    float bev[8];
    #pragma unroll
    for (int nt = 0; nt < 8; ++nt) bev[nt] = bias[nt * 16 + lane16];

    const long wrow = ((long)blockIdx.x * 4 + wv) * 64;

    for (int it = 0; it < 4; ++it) {
        const long rbase = wrow + it * 16;
        const long arow  = rbase + lane16;
        const float* pe = X1 + arow * 128 + quad * 8;
        const float* ph = X2 + arow * 128 + quad * 8;

        // a[kk] holds A[row][kk*32 + quad*8 + j]  (bf16-rounded)
        bf16x8 a[8];
        #pragma unroll
        for (int kk = 0; kk < 4; ++kk) {
            f32x4 u0 = *(const f32x4*)(pe + kk * 32);
            f32x4 u1 = *(const f32x4*)(pe + kk * 32 + 4);
            bf16x8 aa;
            #pragma unroll
            for (int j = 0; j < 4; ++j) { aa[j] = (bf16_t)u0[j]; aa[j + 4] = (bf16_t)u1[j]; }
            a[kk] = aa;
        }
        #pragma unroll
        for (int kk = 0; kk < 4; ++kk) {
            f32x4 u0 = *(const f32x4*)(ph + kk * 32);
            f32x4 u1 = *(const f32x4*)(ph + kk * 32 + 4);
            bf16x8 aa;
            #pragma unroll
            for (int j = 0; j < 4; ++j) { aa[j] = (bf16_t)u0[j]; aa[j + 4] = (bf16_t)u1[j]; }
            a[kk + 4] = aa;
        }

        f32x4 acc[8];
        #pragma unroll
        for (int nt = 0; nt < 8; ++nt) acc[nt] = (f32x4){0.f, 0.f, 0.f, 0.f};

        #pragma unroll
        for (int kk = 0; kk < 8; ++kk) {
            #pragma unroll
            for (int nt = 0; nt < 8; ++nt) {
                int n = nt * 16 + lane16;
                int c = kk * 4 + quad;
                bf16x8 bfrag = *(const bf16x8*)(&lds[n * 256 + (c ^ (n & 7)) * 8]);
                acc[nt] = __builtin_amdgcn_mfma_f32_16x16x32_bf16(a[kk], bfrag, acc[nt], 0, 0, 0);
            }
        }

        // D layout: col = lane&15, row = quad*4 + reg
        const long orow0 = rbase + quad * 4;
        #pragma unroll
        for (int nt = 0; nt < 8; ++nt) {
            #pragma unroll
            for (int r = 0; r < 4; ++r) {
                out[(orow0 + r) * 128 + nt * 16 + lane16] = acc[nt][r] + bev[nt];
            }
        }
    }
}

// ---------------------------------------------------------------------------
// per (b,j):  mx[d] = max(b_m2[d], max_{i: adj[b,i,j]>0} m2[b,i,d])
//             ret   = h1[b,j,d] + b_o2[d] + sum_k (m1[b,j,k]+mx[k]) * W_o2[k][d]
// ---------------------------------------------------------------------------
__global__ void ret_kernel(
    const int* __restrict__ adj,
    const float* __restrict__ m2, const float* __restrict__ m1,
    const float* __restrict__ h1,
    const float* __restrict__ W_o2, const float* __restrict__ b_o2,
    const float* __restrict__ b_m2,
    float* __restrict__ out)
{
    __shared__ float sv[128];
    __shared__ int adjc[256];

    const int bj = blockIdx.x;       // b*N + j
    const int b  = bj >> 8;
    const int j  = bj & 255;
    const int d  = threadIdx.x;      // 0..127

    adjc[d]       = adj[(b * 256 + d) * 256 + j];
    adjc[d + 128] = adj[(b * 256 + d + 128) * 256 + j];
    __syncthreads();

    // virtual node (always connected, zero features) contributes b_m2
    float mx = b_m2[d];
    const float* m2b = m2 + (long)b * 256 * 128 + d;
    for (int i = 0; i < 256; ++i) {
        if (adjc[i] != 0) {                   // block-uniform branch
            mx = fmaxf(mx, m2b[i * 128]);
        }
    }

    sv[d] = m1[bj * 128 + d] + mx;
    __syncthreads();

    float r = h1[bj * 128 + d] + b_o2[d];
    #pragma unroll 8
    for (int k = 0; k < 128; ++k)
        r += sv[k] * W_o2[k * 128 + d];

    out[bj * 128 + d] = r;
}

// ---------------------------------------------------------------------------
extern "C" void kernel_launch(void* const* d_in, const int* in_sizes, int n_in,
                              void* d_out, int out_size, void* d_ws, size_t ws_size,
                              hipStream_t stream)
{
    const float* node   = (const float*)d_in[0];
    const float* edge   = (const float*)d_in[1];
    // d_in[2] graph_fts: unused by the reference
    const int*   adj    = (const int*)d_in[3];
    const float* hidden = (const float*)d_in[4];
    const float* ehid   = (const float*)d_in[5];
    const float* We     = (const float*)d_in[6];
    const float* be     = (const float*)d_in[7];
    const float* W_m1   = (const float*)d_in[8];
    const float* b_m1   = (const float*)d_in[9];
    const float* W_m2   = (const float*)d_in[10];
    const float* b_m2   = (const float*)d_in[11];
    const float* W_o1   = (const float*)d_in[12];
    const float* b_o1   = (const float*)d_in[13];
    const float* W_o2   = (const float*)d_in[14];
    const float* b_o2   = (const float*)d_in[15];

    float* out_ret = (float*)d_out;                     // [8,256,128]
    float* out_et  = (float*)d_out + Bn * Nn * Dn;      // [8,256,256,128]

    float* ws_m2 = (float*)d_ws;                        // [2048,128]
    float* ws_m1 = ws_m2 + 2048 * 128;
    float* ws_h1 = ws_m1 + 2048 * 128;                  // 3 MB total

    // dominant edge GEMM: [524288,256] x [256,128]
    hipLaunchKernelGGL(mfma_gemm_kernel, dim3(2048), dim3(256), 0, stream,
                       edge, ehid, We, be, out_et);
    // node GEMMs: [2048,256] x [256,128], three weight sets
    hipLaunchKernelGGL(mfma_gemm_kernel, dim3(8), dim3(256), 0, stream,
                       node, hidden, W_m2, b_m2, ws_m2);
    hipLaunchKernelGGL(mfma_gemm_kernel, dim3(8), dim3(256), 0, stream,
                       node, hidden, W_m1, b_m1, ws_m1);
    hipLaunchKernelGGL(mfma_gemm_kernel, dim3(8), dim3(256), 0, stream,
                       node, hidden, W_o1, b_o1, ws_h1);
    // adjacency max + output GEMV
    hipLaunchKernelGGL(ret_kernel, dim3(2048), dim3(128), 0, stream,
                       adj, ws_m2, ws_m1, ws_h1, W_o2, b_o2, b_m2, out_ret);
}